// Round 1
// baseline (572.465 us; speedup 1.0000x reference)
//
#include <hip/hip_runtime.h>

#define BB 2
#define NN 256
#define DD 512
#define HH 8

__device__ inline float4 f4fma(float s, float4 a, float4 acc) {
    acc.x += s * a.x; acc.y += s * a.y; acc.z += s * a.z; acc.w += s * a.w;
    return acc;
}

// ---------------- Kernel A: q,k,v projections + qkp ----------------
// grid 128, block 256; 4 rows per block
__global__ __launch_bounds__(256) void kA(
    const float* __restrict__ x,
    const float* __restrict__ wq, const float* __restrict__ bq,
    const float* __restrict__ wk, const float* __restrict__ bk,
    const float* __restrict__ wv, const float* __restrict__ bv,
    const float* __restrict__ wrk,
    float* __restrict__ q, float* __restrict__ k, float* __restrict__ v,
    float* __restrict__ qkp)
{
    __shared__ float4 x4[4 * 128];   // 4 rows of x
    __shared__ float qrow[4 * 512];  // q rows for qkp step
    const int t = threadIdx.x;
    const int row0 = blockIdx.x * 4;

    const float4* xs = (const float4*)(x + row0 * DD);
    for (int j = 0; j < 2; ++j) x4[t + 256 * j] = xs[t + 256 * j];
    __syncthreads();

    const float* W[3]  = {wq, wk, wv};
    const float* Bs[3] = {bq, bk, bv};
    float* O[3]        = {q, k, v};
    for (int pj = 0; pj < 6; ++pj) {
        const int proj = pj >> 1;
        const int col  = (pj & 1) * 256 + t;
        const float4* w4 = (const float4*)(W[proj] + col * DD);
        float acc[4] = {0.f, 0.f, 0.f, 0.f};
        for (int e4 = 0; e4 < 128; ++e4) {
            float4 w = w4[e4];
            for (int r = 0; r < 4; ++r) {
                float4 a = x4[r * 128 + e4];
                acc[r] += w.x * a.x + w.y * a.y + w.z * a.z + w.w * a.w;
            }
        }
        const float bias = Bs[proj][col];
        for (int r = 0; r < 4; ++r) {
            float val = acc[r] + bias;
            O[proj][(row0 + r) * DD + col] = val;
            if (proj == 0) qrow[r * 512 + col] = val;
        }
    }
    __syncthreads();

    // qkp[row,h,e] = sum_d q[row, h*64+d] * wrk[h*64+d, e]
    for (int h = 0; h < 8; ++h) {
        float a0[4] = {0.f, 0.f, 0.f, 0.f};
        float a1[4] = {0.f, 0.f, 0.f, 0.f};
        for (int d = 0; d < 64; ++d) {
            const float* wr = wrk + (h * 64 + d) * DD;
            const float w0 = wr[t];
            const float w1 = wr[t + 256];
            for (int r = 0; r < 4; ++r) {
                const float qv = qrow[r * 512 + h * 64 + d];
                a0[r] += qv * w0;
                a1[r] += qv * w1;
            }
        }
        for (int r = 0; r < 4; ++r) {
            qkp[((size_t)(row0 + r) * HH + h) * DD + t]       = a0[r];
            qkp[((size_t)(row0 + r) * HH + h) * DD + t + 256] = a1[r];
        }
    }
}

// ---------------- Kernel C: fused flash attention over G ----------------
// grid B*N (one block per (b,x)), block 256
__global__ __launch_bounds__(256) void kC(
    const float* __restrict__ G,
    const unsigned char* __restrict__ mask,
    const float* __restrict__ q, const float* __restrict__ k, const float* __restrict__ v,
    const float* __restrict__ qkp,
    const float* __restrict__ wrv, const float* __restrict__ brv,
    float* __restrict__ out_mid)
{
    __shared__ float4 g4[8 * 128];    // G tile, XOR-swizzled by row
    __shared__ float4 qkp4[8 * 128];  // qkp, XOR-swizzled by h
    __shared__ float4 q4[128];        // q row, XOR-swizzled; reused as xv later
    __shared__ float4 p4_[16];        // p[8][8]
    __shared__ float s_l[64];
    __shared__ float m_l[8], l_l[8], r_l[8];
    float* p_l = (float*)p4_;

    const int t = threadIdx.x;
    const int bid = blockIdx.x;   // b*N + x
    const int b = bid >> 8;

    // prologue: stage q row and qkp (swizzled to avoid bank conflicts)
    const float4* qs = (const float4*)(q + (size_t)bid * DD);
    if (t < 128) { const int h = t >> 4; q4[t ^ h] = qs[t]; }
    const float4* qkps = (const float4*)(qkp + (size_t)bid * HH * DD);
    for (int j = 0; j < 4; ++j) {
        const int f = t + 256 * j;
        const int h = f >> 7, e4 = f & 127;
        qkp4[h * 128 + (e4 ^ h)] = qkps[f];
    }
    if (t < 8) { m_l[t] = -3.0e38f; l_l[t] = 0.f; }

    float4 gacc[4] = {};
    float vaccx = 0.f, vaccy = 0.f;
    const int hb  = (t >> 7) * 4;   // h-group for g_agg
    const int ec4 = t & 127;        // e float4 slice for g_agg
    const int hv  = t >> 5;         // h for x_v
    const int d2  = (t & 31) * 2;   // d pair for x_v

    const float4* Gsrc = (const float4*)(G + (size_t)bid * NN * DD);
    const unsigned char* mrow = mask + (size_t)bid * NN;

    for (int tt = 0; tt < 32; ++tt) {
        const int y0 = tt * 8;
        __syncthreads();  // prior phase-4 reads of g4 done
        // stage G tile (8 rows x 512) with per-row XOR swizzle
        const float4* gt = Gsrc + y0 * 128;
        for (int j = 0; j < 4; ++j) {
            const int f = t + 256 * j;
            const int y = f >> 7, e4 = f & 127;
            g4[y * 128 + (e4 ^ y)] = gt[f];
        }
        __syncthreads();

        // scores: 2 threads per (y,h)
        if (t < 128) {
            const int pair = t >> 1, sub = t & 1;
            const int y = pair >> 3, h = pair & 7;
            float sum = 0.f;
            for (int k4 = 0; k4 < 64; ++k4) {
                const int e4 = sub * 64 + k4;
                float4 gv = g4[y * 128 + (e4 ^ y)];
                float4 qv = qkp4[h * 128 + (e4 ^ h)];
                sum += gv.x * qv.x + gv.y * qv.y + gv.z * qv.z + gv.w * qv.w;
            }
            const float4* kg = (const float4*)(k + (size_t)(b * NN + y0 + y) * DD + h * 64 + sub * 32);
            for (int i = 0; i < 8; ++i) {
                float4 kv = kg[i];
                float4 qv = q4[(h * 16 + sub * 8 + i) ^ h];
                sum += kv.x * qv.x + kv.y * qv.y + kv.z * qv.z + kv.w * qv.w;
            }
            sum += __shfl_xor(sum, 1);
            if (sub == 0) {
                float sc = sum * 0.125f;  // 1/sqrt(64)
                if (mrow[y0 + y]) sc = -1e9f;
                s_l[y * 8 + h] = sc;
            }
        }
        __syncthreads();

        // online softmax bookkeeping (8 threads, one per h)
        if (t < 8) {
            const int h = t;
            const float m_old = m_l[h];
            float tm = s_l[h];
            for (int y = 1; y < 8; ++y) tm = fmaxf(tm, s_l[y * 8 + h]);
            const float m_new = fmaxf(m_old, tm);
            const float r = expf(m_old - m_new);
            float ls = 0.f;
            for (int y = 0; y < 8; ++y) {
                const float p = expf(s_l[y * 8 + h] - m_new);
                p_l[y * 8 + h] = p;
                ls += p;
            }
            l_l[h] = l_l[h] * r + ls;
            m_l[h] = m_new;
            r_l[h] = r;
        }
        __syncthreads();

        // accumulate g_agg (all 256 threads) and x_v
        {
            const float r0 = r_l[hb], r1 = r_l[hb + 1], r2 = r_l[hb + 2], r3 = r_l[hb + 3];
            gacc[0].x *= r0; gacc[0].y *= r0; gacc[0].z *= r0; gacc[0].w *= r0;
            gacc[1].x *= r1; gacc[1].y *= r1; gacc[1].z *= r1; gacc[1].w *= r1;
            gacc[2].x *= r2; gacc[2].y *= r2; gacc[2].z *= r2; gacc[2].w *= r2;
            gacc[3].x *= r3; gacc[3].y *= r3; gacc[3].z *= r3; gacc[3].w *= r3;
            const float rv = r_l[hv];
            vaccx *= rv; vaccy *= rv;
            for (int y = 0; y < 8; ++y) {
                float4 gv = g4[y * 128 + (ec4 ^ y)];
                float4 pv = p4_[y * 2 + (hb >> 2)];
                gacc[0] = f4fma(pv.x, gv, gacc[0]);
                gacc[1] = f4fma(pv.y, gv, gacc[1]);
                gacc[2] = f4fma(pv.z, gv, gacc[2]);
                gacc[3] = f4fma(pv.w, gv, gacc[3]);
                const float2 vv = *(const float2*)(v + (size_t)(b * NN + y0 + y) * DD + hv * 64 + d2);
                const float ps = p_l[y * 8 + hv];
                vaccx += ps * vv.x; vaccy += ps * vv.y;
            }
        }
    }
    __syncthreads();

    // write g_agg unswizzled into g4 buffer: row h, col ec4
    g4[(hb + 0) * 128 + ec4] = gacc[0];
    g4[(hb + 1) * 128 + ec4] = gacc[1];
    g4[(hb + 2) * 128 + ec4] = gacc[2];
    g4[(hb + 3) * 128 + ec4] = gacc[3];
    // x_v into q4 reused as float[512]
    float* xv = (float*)q4;
    const float linv = 1.f / l_l[hv];
    xv[hv * 64 + d2]     = vaccx * linv;
    xv[hv * 64 + d2 + 1] = vaccy * linv;
    __syncthreads();

    const float* gun = (const float*)g4;
    for (int jj = 0; jj < 2; ++jj) {
        const int o = jj * 256 + t;
        const int h = o >> 6;
        const float4* wr4 = (const float4*)(wrv + (size_t)o * DD);
        const float4* gr4 = (const float4*)(gun + h * DD);
        float acc = 0.f;
        for (int e4 = 0; e4 < 128; ++e4) {
            float4 w = wr4[e4];
            float4 g = gr4[e4];
            acc += w.x * g.x + w.y * g.y + w.z * g.z + w.w * g.w;
        }
        out_mid[(size_t)bid * DD + o] = xv[o] + acc / l_l[h] + brv[o];
    }
}

// ---------------- Kernel D: wo/wl/wr projections of out_mid ----------------
// grid 128, block 256; 4 rows per block
__global__ __launch_bounds__(256) void kD(
    const float* __restrict__ om,
    const float* __restrict__ wo, const float* __restrict__ bo,
    const float* __restrict__ wl, const float* __restrict__ bl,
    const float* __restrict__ wr, const float* __restrict__ br,
    float* __restrict__ fout, float* __restrict__ xl, float* __restrict__ xr)
{
    __shared__ float4 a4[4 * 128];
    const int t = threadIdx.x;
    const int row0 = blockIdx.x * 4;
    const float4* as = (const float4*)(om + (size_t)row0 * DD);
    for (int j = 0; j < 2; ++j) a4[t + 256 * j] = as[t + 256 * j];
    __syncthreads();

    const float* W[3]  = {wo, wl, wr};
    const float* Bs[3] = {bo, bl, br};
    float* O[3]        = {fout, xl, xr};
    for (int pj = 0; pj < 6; ++pj) {
        const int proj = pj >> 1;
        const int col  = (pj & 1) * 256 + t;
        const float4* w4 = (const float4*)(W[proj] + col * DD);
        float acc[4] = {0.f, 0.f, 0.f, 0.f};
        for (int e4 = 0; e4 < 128; ++e4) {
            float4 w = w4[e4];
            for (int r = 0; r < 4; ++r) {
                float4 a = a4[r * 128 + e4];
                acc[r] += w.x * a.x + w.y * a.y + w.z * a.z + w.w * a.w;
            }
        }
        const float bias = Bs[proj][col];
        for (int r = 0; r < 4; ++r) O[proj][(size_t)(row0 + r) * DD + col] = acc[r] + bias;
    }
}

// ---------------- Kernel E: new_graphs = xl[:, :, None, :] + xr[:, None, :, :] ----------------
// grid B*N, block 256
__global__ __launch_bounds__(256) void kE(
    const float* __restrict__ xl, const float* __restrict__ xr,
    float* __restrict__ ng)
{
    const int t = threadIdx.x;
    const int bid = blockIdx.x;  // b*N + x
    const int b = bid >> 8;
    const int o4 = t & 127;
    const int ys = t >> 7;
    const float4 left = ((const float4*)xl)[(size_t)bid * 128 + o4];
    const float4* xr4 = (const float4*)xr + (size_t)b * NN * 128;
    float4* out4 = (float4*)ng + (size_t)bid * NN * 128;
    for (int y = ys; y < NN; y += 2) {
        float4 r = xr4[y * 128 + o4];
        float4 s;
        s.x = left.x + r.x; s.y = left.y + r.y; s.z = left.z + r.z; s.w = left.w + r.w;
        out4[y * 128 + o4] = s;
    }
}

extern "C" void kernel_launch(void* const* d_in, const int* in_sizes, int n_in,
                              void* d_out, int out_size, void* d_ws, size_t ws_size,
                              hipStream_t stream)
{
    const float* x    = (const float*)d_in[0];
    const float* G    = (const float*)d_in[1];
    const unsigned char* mask = (const unsigned char*)d_in[2];
    const float* wq  = (const float*)d_in[3];  const float* bq  = (const float*)d_in[4];
    const float* wk  = (const float*)d_in[5];  const float* bk  = (const float*)d_in[6];
    const float* wv  = (const float*)d_in[7];  const float* bv  = (const float*)d_in[8];
    const float* wo  = (const float*)d_in[9];  const float* bo  = (const float*)d_in[10];
    const float* wl  = (const float*)d_in[11]; const float* bl  = (const float*)d_in[12];
    const float* wr  = (const float*)d_in[13]; const float* br  = (const float*)d_in[14];
    const float* wrk = (const float*)d_in[15]; /* brk = d_in[16] unused: softmax-invariant */
    const float* wrv = (const float*)d_in[17]; const float* brv = (const float*)d_in[18];

    float* out  = (float*)d_out;
    float* fout = out;                          // [B,N,D]
    float* ng   = out + (size_t)BB * NN * DD;   // [B,N,N,D]

    // bulk scratch lives in the TAIL of the new_graphs region: it is consumed
    // by kC/kD strictly before kE overwrites the whole region.
    const size_t ng_floats   = (size_t)BB * NN * NN * DD;             // 67,108,864
    const size_t row_floats  = (size_t)BB * NN * DD;                  // 262,144
    const size_t qkp_floats  = (size_t)BB * NN * HH * DD;             // 2,097,152
    const size_t bulk_floats = 3 * row_floats + qkp_floats + row_floats;
    float* bulk = ng + ng_floats - bulk_floats;
    float* q   = bulk;
    float* k   = q + row_floats;
    float* v   = k + row_floats;
    float* qkp = v + row_floats;
    float* om  = qkp + qkp_floats;
    // xl/xr must survive through kE -> d_ws (2 MB)
    float* xl = (float*)d_ws;
    float* xr = xl + row_floats;

    kA<<<128, 256, 0, stream>>>(x, wq, bq, wk, bk, wv, bv, wrk, q, k, v, qkp);
    kC<<<BB * NN, 256, 0, stream>>>(G, mask, q, k, v, qkp, wrv, brv, om);
    kD<<<128, 256, 0, stream>>>(om, wo, bo, wl, bl, wr, br, fout, xl, xr);
    kE<<<BB * NN, 256, 0, stream>>>(xl, xr, ng);
}

// Round 2
// 437.574 us; speedup vs baseline: 1.3083x; 1.3083x over previous
//
#include <hip/hip_runtime.h>

#define BB 2
#define NN 256
#define DD 512
#define HH 8

__device__ __forceinline__ float dot4(float4 a, float4 b) {
    return a.x*b.x + a.y*b.y + a.z*b.z + a.w*b.w;
}

__device__ __forceinline__ void gload_lds16(const void* g, void* l) {
    __builtin_amdgcn_global_load_lds(
        (const __attribute__((address_space(1))) unsigned int*)g,
        (__attribute__((address_space(3))) unsigned int*)l, 16, 0, 0);
}

// Stage 8 rows x 512 floats (16KB) global->LDS with per-row XOR swizzle.
// LDS slot (y, c) receives source element (y, c^y)  ==> element (y,e4) lands
// at slot (y, e4^y). Dest is linear (wave-uniform base + lane*16), source is
// per-lane pre-swizzled (guide m173 pattern).
__device__ __forceinline__ void stage_swz(const char* rowbase, float4* dst, int w, int lane) {
    #pragma unroll
    for (int j = 0; j < 4; ++j) {
        const int f0 = w * 256 + j * 64;
        const int y = f0 >> 7;
        const int c = (f0 & 127) + lane;
        gload_lds16(rowbase + (size_t)y * 2048 + ((size_t)(c ^ y) << 4), &dst[f0]);
    }
}

// ---------------- kProj: 3 linear layers, column-partitioned ----------------
// grid 256 = 32 rowgroups(16 rows) x 8 colquarters(64 cols); block 256
__global__ __launch_bounds__(256) void kProj(
    const float* __restrict__ in_,
    const float* __restrict__ w0, const float* __restrict__ b0,
    const float* __restrict__ w1, const float* __restrict__ b1,
    const float* __restrict__ w2, const float* __restrict__ b2,
    float* __restrict__ o0, float* __restrict__ o1, float* __restrict__ o2)
{
    __shared__ float4 xs[16 * 128];
    const int t = threadIdx.x;
    const int rowg = blockIdx.x >> 3;
    const int colq = blockIdx.x & 7;
    const int row0 = rowg * 16;
    const float4* src = (const float4*)(in_ + (size_t)row0 * DD);
    #pragma unroll
    for (int j = 0; j < 8; ++j) xs[t + 256 * j] = src[t + 256 * j];
    __syncthreads();
    const int c  = colq * 64 + (t & 63);
    const int rb = (t >> 6) * 4;
    const float* Ws[3] = {w0, w1, w2};
    const float* Bs[3] = {b0, b1, b2};
    float* Os[3]       = {o0, o1, o2};
    #pragma unroll
    for (int p = 0; p < 3; ++p) {
        const float4* w4 = (const float4*)(Ws[p] + (size_t)c * DD);
        float a0 = 0, a1 = 0, a2 = 0, a3 = 0;
        #pragma unroll 4
        for (int e4 = 0; e4 < 128; ++e4) {
            const float4 wv = w4[e4];
            a0 += dot4(wv, xs[(rb + 0) * 128 + e4]);
            a1 += dot4(wv, xs[(rb + 1) * 128 + e4]);
            a2 += dot4(wv, xs[(rb + 2) * 128 + e4]);
            a3 += dot4(wv, xs[(rb + 3) * 128 + e4]);
        }
        const float bias = Bs[p][c];
        Os[p][(size_t)(row0 + rb + 0) * DD + c] = a0 + bias;
        Os[p][(size_t)(row0 + rb + 1) * DD + c] = a1 + bias;
        Os[p][(size_t)(row0 + rb + 2) * DD + c] = a2 + bias;
        Os[p][(size_t)(row0 + rb + 3) * DD + c] = a3 + bias;
    }
}

// ---------------- kQkp: qkp[row,h,e] = sum_d q[row,h*64+d]*wrk[h*64+d,e] ----
// grid 256 = 64 rowgroups(8 rows) x 4 e-quarters(128); block 256
__global__ __launch_bounds__(256) void kQkp(
    const float* __restrict__ q, const float* __restrict__ wrk,
    float* __restrict__ qkp)
{
    __shared__ float qs[8 * 512];
    const int t = threadIdx.x;
    const int rowg = blockIdx.x >> 2;
    const int eq = blockIdx.x & 3;
    const int row0 = rowg * 8;
    {
        float4* qs4 = (float4*)qs;
        const float4* src = (const float4*)(q + (size_t)row0 * DD);
        #pragma unroll
        for (int j = 0; j < 4; ++j) qs4[t + 256 * j] = src[t + 256 * j];
    }
    __syncthreads();
    const int e  = eq * 128 + (t & 127);
    const int rb = (t >> 7) * 4;
    for (int h = 0; h < 8; ++h) {
        float a0 = 0, a1 = 0, a2 = 0, a3 = 0;
        const float* wrow = wrk + (size_t)(h * 64) * DD + e;
        const float* q0 = qs + (rb + 0) * 512 + h * 64;
        const float* q1 = qs + (rb + 1) * 512 + h * 64;
        const float* q2 = qs + (rb + 2) * 512 + h * 64;
        const float* q3 = qs + (rb + 3) * 512 + h * 64;
        #pragma unroll 8
        for (int d = 0; d < 64; ++d) {
            const float wv = wrow[(size_t)d * DD];
            a0 += q0[d] * wv; a1 += q1[d] * wv; a2 += q2[d] * wv; a3 += q3[d] * wv;
        }
        qkp[((size_t)(row0 + rb + 0) * HH + h) * DD + e] = a0;
        qkp[((size_t)(row0 + rb + 1) * HH + h) * DD + e] = a1;
        qkp[((size_t)(row0 + rb + 2) * HH + h) * DD + e] = a2;
        qkp[((size_t)(row0 + rb + 3) * HH + h) * DD + e] = a3;
    }
}

// ---------------- kSk: skpre[b,x,h,y] = 0.125*(q.k) + mask ----------------
// grid 256 = 2 b x 32 xt(8 rows) x 4 yt(64); block 256
__global__ __launch_bounds__(256) void kSk(
    const float* __restrict__ q, const float* __restrict__ k,
    const unsigned char* __restrict__ mask, float* __restrict__ sk)
{
    __shared__ float qs[8 * 65];
    __shared__ float ks[64 * 65];
    const int t = threadIdx.x;
    const int blk = blockIdx.x;
    const int b  = blk >> 7;
    const int xt = (blk >> 2) & 31;
    const int yt = blk & 3;
    const int x0 = xt * 8, y0 = yt * 64;
    for (int h = 0; h < 8; ++h) {
        if (t < 128) {
            const int xi = t >> 4, d = (t & 15) * 4;
            const float4 tmp = *(const float4*)(q + (size_t)(b * NN + x0 + xi) * DD + h * 64 + d);
            qs[xi * 65 + d + 0] = tmp.x; qs[xi * 65 + d + 1] = tmp.y;
            qs[xi * 65 + d + 2] = tmp.z; qs[xi * 65 + d + 3] = tmp.w;
        }
        #pragma unroll
        for (int j = 0; j < 4; ++j) {
            const int f = t + 256 * j;
            const int yi = f >> 4, d = (f & 15) * 4;
            const float4 tmp = *(const float4*)(k + (size_t)(b * NN + y0 + yi) * DD + h * 64 + d);
            ks[yi * 65 + d + 0] = tmp.x; ks[yi * 65 + d + 1] = tmp.y;
            ks[yi * 65 + d + 2] = tmp.z; ks[yi * 65 + d + 3] = tmp.w;
        }
        __syncthreads();
        const int xi = t >> 5, yg = t & 31;
        float a0 = 0, a1 = 0;
        #pragma unroll 8
        for (int d = 0; d < 64; ++d) {
            const float qv = qs[xi * 65 + d];
            a0 += qv * ks[(yg * 2 + 0) * 65 + d];
            a1 += qv * ks[(yg * 2 + 1) * 65 + d];
        }
        a0 *= 0.125f; a1 *= 0.125f;
        const unsigned char* mrow = mask + (size_t)(b * NN + x0 + xi) * NN;
        const int gy = y0 + yg * 2;
        if (mrow[gy + 0]) a0 = -1e9f;
        if (mrow[gy + 1]) a1 = -1e9f;
        float2 st; st.x = a0; st.y = a1;
        *(float2*)(sk + ((size_t)(b * NN + x0 + xi) * HH + h) * NN + gy) = st;
        __syncthreads();
    }
}

// ---------------- kC: flash attention over G, split-K 4 parts -------------
// grid 2048 = (b*N) x 4 parts; block 256; each block handles 64 y rows
__global__ __launch_bounds__(256) void kC(
    const float* __restrict__ G, const float* __restrict__ sk,
    const float* __restrict__ qkp, const float* __restrict__ v,
    float* __restrict__ pg, float* __restrict__ pxv,
    float* __restrict__ pm, float* __restrict__ pl)
{
    __shared__ float4 gbuf[2][1024];   // double-buffered 8x512 G tile, swizzled
    __shared__ float4 qk4[1024];       // qkp [8h][128], swizzled
    __shared__ float s_l[64];          // scores [8y][8h]

    const int t = threadIdx.x;
    const int lane = t & 63;
    const int w = t >> 6;
    const int blk = blockIdx.x;
    const int part = blk & 3;
    const int bid = blk >> 2;          // b*N + x
    const int b = bid >> 8;
    const int ybase = part * 64;

    const char* Grow = (const char*)(G + (size_t)bid * NN * DD);
    stage_swz((const char*)(qkp + (size_t)bid * HH * DD), qk4, w, lane);
    stage_swz(Grow + (size_t)ybase * 2048, &gbuf[0][0], w, lane);
    __syncthreads();

    // score-phase ids (2y x 2h register block, 16-lane slice)
    const int s_  = t & 15;
    const int h0i = ((t >> 4) & 3) * 2;
    const int y0i = w * 2;
    // accumulate-phase ids
    const int ec4 = t & 127;
    const int hb  = (t >> 7) * 4;
    const int hv  = t >> 5;
    const int d2  = (t & 31) * 2;

    float4 gacc0 = {0,0,0,0}, gacc1 = {0,0,0,0}, gacc2 = {0,0,0,0}, gacc3 = {0,0,0,0};
    float m0 = -3e38f, m1 = -3e38f, m2 = -3e38f, m3 = -3e38f;
    float l0 = 0, l1 = 0, l2 = 0, l3 = 0;
    float vx = 0, vy = 0, mvold = -3e38f;

    const float* vrow = v + (size_t)(b * NN + ybase) * DD + hv * 64 + d2;
    const float* skrow = sk + (size_t)bid * HH * NN;

    int cb = 0;
    for (int tt = 0; tt < 8; ++tt) {
        if (tt < 7)
            stage_swz(Grow + (size_t)(ybase + (tt + 1) * 8) * 2048, &gbuf[cb ^ 1][0], w, lane);

        // ---- scores ----
        {
            float a00 = 0, a01 = 0, a10 = 0, a11 = 0;
            const float4* gb = &gbuf[cb][0];
            #pragma unroll
            for (int i = 0; i < 8; ++i) {
                const int e4 = i * 16 + s_;
                const float4 g0 = gb[y0i * 128 + (e4 ^ y0i)];
                const float4 g1 = gb[(y0i + 1) * 128 + (e4 ^ (y0i + 1))];
                const float4 p0 = qk4[h0i * 128 + (e4 ^ h0i)];
                const float4 p1 = qk4[(h0i + 1) * 128 + (e4 ^ (h0i + 1))];
                a00 += dot4(g0, p0); a01 += dot4(g0, p1);
                a10 += dot4(g1, p0); a11 += dot4(g1, p1);
            }
            #pragma unroll
            for (int mm = 1; mm < 16; mm <<= 1) {
                a00 += __shfl_xor(a00, mm); a01 += __shfl_xor(a01, mm);
                a10 += __shfl_xor(a10, mm); a11 += __shfl_xor(a11, mm);
            }
            if (s_ < 4) {
                const int yy = s_ & 1, hh = s_ >> 1;
                const float val = yy ? (hh ? a11 : a10) : (hh ? a01 : a00);
                const int gy = ybase + tt * 8 + y0i + yy;
                const int h = h0i + hh;
                s_l[(y0i + yy) * 8 + h] = val * 0.125f + skrow[(size_t)h * NN + gy];
            }
        }
        __syncthreads();

        // ---- per-thread softmax update + accumulate ----
        {
            {   const float tmx0 = fmaxf(fmaxf(fmaxf(s_l[0*8+hb+0], s_l[1*8+hb+0]), fmaxf(s_l[2*8+hb+0], s_l[3*8+hb+0])),
                                         fmaxf(fmaxf(s_l[4*8+hb+0], s_l[5*8+hb+0]), fmaxf(s_l[6*8+hb+0], s_l[7*8+hb+0])));
                const float mn = fmaxf(m0, tmx0); const float rs = __expf(m0 - mn);
                m0 = mn; l0 *= rs; gacc0.x *= rs; gacc0.y *= rs; gacc0.z *= rs; gacc0.w *= rs; }
            {   const float tmx1 = fmaxf(fmaxf(fmaxf(s_l[0*8+hb+1], s_l[1*8+hb+1]), fmaxf(s_l[2*8+hb+1], s_l[3*8+hb+1])),
                                         fmaxf(fmaxf(s_l[4*8+hb+1], s_l[5*8+hb+1]), fmaxf(s_l[6*8+hb+1], s_l[7*8+hb+1])));
                const float mn = fmaxf(m1, tmx1); const float rs = __expf(m1 - mn);
                m1 = mn; l1 *= rs; gacc1.x *= rs; gacc1.y *= rs; gacc1.z *= rs; gacc1.w *= rs; }
            {   const float tmx2 = fmaxf(fmaxf(fmaxf(s_l[0*8+hb+2], s_l[1*8+hb+2]), fmaxf(s_l[2*8+hb+2], s_l[3*8+hb+2])),
                                         fmaxf(fmaxf(s_l[4*8+hb+2], s_l[5*8+hb+2]), fmaxf(s_l[6*8+hb+2], s_l[7*8+hb+2])));
                const float mn = fmaxf(m2, tmx2); const float rs = __expf(m2 - mn);
                m2 = mn; l2 *= rs; gacc2.x *= rs; gacc2.y *= rs; gacc2.z *= rs; gacc2.w *= rs; }
            {   const float tmx3 = fmaxf(fmaxf(fmaxf(s_l[0*8+hb+3], s_l[1*8+hb+3]), fmaxf(s_l[2*8+hb+3], s_l[3*8+hb+3])),
                                         fmaxf(fmaxf(s_l[4*8+hb+3], s_l[5*8+hb+3]), fmaxf(s_l[6*8+hb+3], s_l[7*8+hb+3])));
                const float mn = fmaxf(m3, tmx3); const float rs = __expf(m3 - mn);
                m3 = mn; l3 *= rs; gacc3.x *= rs; gacc3.y *= rs; gacc3.z *= rs; gacc3.w *= rs; }

            const int ri = hv & 3;
            const float mv = (ri & 2) ? ((ri & 1) ? m3 : m2) : ((ri & 1) ? m1 : m0);
            const float rv = __expf(mvold - mv);
            vx *= rv; vy *= rv; mvold = mv;

            const float4* gb = &gbuf[cb][0];
            const float* vt = vrow + (size_t)tt * 8 * DD;
            #pragma unroll
            for (int y = 0; y < 8; ++y) {
                const float4 gv = gb[y * 128 + (ec4 ^ y)];
                const float2 vv = *(const float2*)(vt + (size_t)y * DD);
                const float p0 = __expf(s_l[y*8 + hb + 0] - m0); l0 += p0;
                gacc0.x += p0*gv.x; gacc0.y += p0*gv.y; gacc0.z += p0*gv.z; gacc0.w += p0*gv.w;
                const float p1 = __expf(s_l[y*8 + hb + 1] - m1); l1 += p1;
                gacc1.x += p1*gv.x; gacc1.y += p1*gv.y; gacc1.z += p1*gv.z; gacc1.w += p1*gv.w;
                const float p2 = __expf(s_l[y*8 + hb + 2] - m2); l2 += p2;
                gacc2.x += p2*gv.x; gacc2.y += p2*gv.y; gacc2.z += p2*gv.z; gacc2.w += p2*gv.w;
                const float p3 = __expf(s_l[y*8 + hb + 3] - m3); l3 += p3;
                gacc3.x += p3*gv.x; gacc3.y += p3*gv.y; gacc3.z += p3*gv.z; gacc3.w += p3*gv.w;
                const float pv = __expf(s_l[y*8 + hv] - mv);
                vx += pv * vv.x; vy += pv * vv.y;
            }
        }
        __syncthreads();
        cb ^= 1;
    }

    // epilogue: unnormalized partials (relative to per-block running max)
    float4* pgb = (float4*)pg + (size_t)blk * 1024;
    pgb[(hb + 0) * 128 + ec4] = gacc0;
    pgb[(hb + 1) * 128 + ec4] = gacc1;
    pgb[(hb + 2) * 128 + ec4] = gacc2;
    pgb[(hb + 3) * 128 + ec4] = gacc3;
    float2 xvst; xvst.x = vx; xvst.y = vy;
    *(float2*)(pxv + (size_t)blk * DD + hv * 64 + d2) = xvst;
    if ((t & 127) == 0) {
        const int base = blk * 8 + hb;
        pm[base + 0] = m0; pm[base + 1] = m1; pm[base + 2] = m2; pm[base + 3] = m3;
        pl[base + 0] = l0; pl[base + 1] = l1; pl[base + 2] = l2; pl[base + 3] = l3;
    }
}

// ---------------- kM: merge 4 partials + wrv GEMV epilogue ----------------
// grid 512 (one per b,x); block 256
__global__ __launch_bounds__(256) void kM(
    const float* __restrict__ pg, const float* __restrict__ pxv,
    const float* __restrict__ pm, const float* __restrict__ pl,
    const float* __restrict__ wrv, const float* __restrict__ brv,
    float* __restrict__ om)
{
    __shared__ float4 gc[1024];     // combined g_agg [8h][128]
    __shared__ float xvs[512];
    __shared__ float mlds[32], llds[32], wexp[32], Ls[8];
    const int t = threadIdx.x;
    const int bid = blockIdx.x;
    if (t < 32) { mlds[t] = pm[bid * 32 + t]; llds[t] = pl[bid * 32 + t]; }
    __syncthreads();
    if (t < 8) {
        float M = mlds[t];
        #pragma unroll
        for (int i = 1; i < 4; ++i) M = fmaxf(M, mlds[i * 8 + t]);
        float L = 0;
        #pragma unroll
        for (int i = 0; i < 4; ++i) {
            const float wv = __expf(mlds[i * 8 + t] - M);
            wexp[i * 8 + t] = wv;
            L += wv * llds[i * 8 + t];
        }
        Ls[t] = L;
    }
    __syncthreads();
    const int c4 = t & 127;
    const int hq = t >> 7;
    #pragma unroll
    for (int r = 0; r < 4; ++r) {
        const int h = hq * 4 + r;
        float4 acc = {0, 0, 0, 0};
        #pragma unroll
        for (int i = 0; i < 4; ++i) {
            const float wv = wexp[i * 8 + h];
            const float4 g = ((const float4*)pg)[((size_t)bid * 4 + i) * 1024 + h * 128 + c4];
            acc.x += wv * g.x; acc.y += wv * g.y; acc.z += wv * g.z; acc.w += wv * g.w;
        }
        gc[h * 128 + c4] = acc;
    }
    {
        const int d = t * 2;
        const int h = d >> 6;
        float sx = 0, sy = 0;
        #pragma unroll
        for (int i = 0; i < 4; ++i) {
            const float wv = wexp[i * 8 + h];
            const float2 pv = *(const float2*)(pxv + ((size_t)bid * 4 + i) * DD + d);
            sx += wv * pv.x; sy += wv * pv.y;
        }
        xvs[d] = sx; xvs[d + 1] = sy;
    }
    __syncthreads();
    #pragma unroll
    for (int jj = 0; jj < 2; ++jj) {
        const int o = jj * 256 + t;
        const int h = o >> 6;
        const float4* wr4 = (const float4*)(wrv + (size_t)o * DD);
        float acc = 0;
        #pragma unroll 4
        for (int e4 = 0; e4 < 128; ++e4) acc += dot4(wr4[e4], gc[h * 128 + e4]);
        om[(size_t)bid * DD + o] = (xvs[o] + acc) / Ls[h] + brv[o];
    }
}

// ---------------- kE: new_graphs = xl[:,:,None,:] + xr[:,None,:,:] -------
// grid 2048 = 512 bid x 4 y-chunks; block 256
__global__ __launch_bounds__(256) void kE(
    const float* __restrict__ xl, const float* __restrict__ xr,
    float* __restrict__ ng)
{
    const int t = threadIdx.x;
    const int blk = blockIdx.x;
    const int bid = blk >> 2;
    const int yc = blk & 3;
    const int b = bid >> 8;
    const int o4 = t & 127;
    const int yh = t >> 7;
    const float4 left = ((const float4*)xl)[(size_t)bid * 128 + o4];
    const float4* xr4 = (const float4*)xr + (size_t)b * NN * 128;
    float4* out4 = (float4*)ng + (size_t)bid * NN * 128;
    for (int y = yc * 64 + yh; y < yc * 64 + 64; y += 2) {
        const float4 rr = xr4[y * 128 + o4];
        float4 s;
        s.x = left.x + rr.x; s.y = left.y + rr.y;
        s.z = left.z + rr.z; s.w = left.w + rr.w;
        out4[y * 128 + o4] = s;
    }
}

extern "C" void kernel_launch(void* const* d_in, const int* in_sizes, int n_in,
                              void* d_out, int out_size, void* d_ws, size_t ws_size,
                              hipStream_t stream)
{
    (void)in_sizes; (void)n_in; (void)out_size; (void)ws_size;
    const float* x    = (const float*)d_in[0];
    const float* G    = (const float*)d_in[1];
    const unsigned char* mask = (const unsigned char*)d_in[2];
    const float* wq  = (const float*)d_in[3];  const float* bq  = (const float*)d_in[4];
    const float* wk  = (const float*)d_in[5];  const float* bk  = (const float*)d_in[6];
    const float* wv  = (const float*)d_in[7];  const float* bv  = (const float*)d_in[8];
    const float* wo  = (const float*)d_in[9];  const float* bo  = (const float*)d_in[10];
    const float* wl  = (const float*)d_in[11]; const float* bl  = (const float*)d_in[12];
    const float* wr  = (const float*)d_in[13]; const float* br  = (const float*)d_in[14];
    const float* wrk = (const float*)d_in[15]; /* brk unused: softmax-invariant */
    const float* wrv = (const float*)d_in[17]; const float* brv = (const float*)d_in[18];

    float* out  = (float*)d_out;
    float* fout = out;                          // [B,N,D]
    float* ng   = out + (size_t)BB * NN * DD;   // [B,N,N,D]

    // Scratch in the tail of the ng region: all consumed before kE overwrites.
    const size_t ng_f  = (size_t)BB * NN * NN * DD;   // 67,108,864
    const size_t row_f = (size_t)BB * NN * DD;        // 262,144
    const size_t total = row_f * 52 + 32768;          // 13,664,256 floats
    float* base = ng + ng_f - total;
    float* q    = base;
    float* k    = q   + row_f;
    float* vv_  = k   + row_f;
    float* qkp  = vv_ + row_f;          // row_f * 8
    float* skp  = qkp + row_f * 8;      // row_f * 4
    float* pg   = skp + row_f * 4;      // row_f * 32
    float* pxv  = pg  + row_f * 32;     // row_f * 4
    float* pm   = pxv + row_f * 4;      // 16384
    float* pl   = pm  + 16384;          // 16384
    float* om   = pl  + 16384;          // row_f
    float* xl = (float*)d_ws;           // survives into kE -> d_ws
    float* xr = xl + row_f;

    kProj<<<256, 256, 0, stream>>>(x, wq, bq, wk, bk, wv, bv, q, k, vv_);
    kQkp <<<256, 256, 0, stream>>>(q, wrk, qkp);
    kSk  <<<256, 256, 0, stream>>>(q, k, mask, skp);
    kC   <<<2048, 256, 0, stream>>>(G, skp, qkp, vv_, pg, pxv, pm, pl);
    kM   <<<512, 256, 0, stream>>>(pg, pxv, pm, pl, wrv, brv, om);
    kProj<<<256, 256, 0, stream>>>(om, wo, bo, wl, bl, wr, br, fout, xl, xr);
    kE   <<<2048, 256, 0, stream>>>(xl, xr, ng);
}